// Round 4
// baseline (144.851 us; speedup 1.0000x reference)
//
#include <hip/hip_runtime.h>
#include <math.h>

// LRPCHead: C=512, H=W=160 (HW=25600), NC=1203, LC=64
// Outputs (flat, fp32): loc_out [64*25600] | cls_out [1203*25600] | mask [25600]

constexpr int C_   = 512;
constexpr int HW_  = 25600;
constexpr int NC_  = 1203;

constexpr int LOC_OFF_  = 0;
constexpr int CLS_OFF_  = 64 * HW_;              // 1,638,400
constexpr int MASK_OFF_ = CLS_OFF_ + NC_ * HW_;  // 32,435,200

typedef float vfloat4 __attribute__((ext_vector_type(4)));

// ---------------------------------------------------------------- init
__global__ void k_init(int* cnt) { *cnt = 0; }

// ------------------------------------------------- pf score + mask + compact
// block = 256 threads = 64 hw-columns x 4 C-slices of 128
__global__ __launch_bounds__(256) void k_pf_mask(
    const float* __restrict__ cls_feat, const float* __restrict__ pf_w,
    const float* __restrict__ pf_b, const float* __restrict__ conf,
    float* __restrict__ out, int* __restrict__ cnt,
    int* __restrict__ idxList)
{
    __shared__ double sPart[256];
    const int tid   = threadIdx.x;
    const int hwi   = tid & 63;
    const int slice = tid >> 6;
    const int hw    = blockIdx.x * 64 + hwi;
    const float* p  = cls_feat + (size_t)slice * 128 * HW_ + hw;
    const float* w  = pf_w + slice * 128;
    double acc = 0.0;
    #pragma unroll 4
    for (int k = 0; k < 128; ++k)
        acc += (double)w[k] * (double)p[(size_t)k * HW_];
    sPart[tid] = acc;
    __syncthreads();
    if (slice == 0) {
        double s = sPart[hwi] + sPart[64 + hwi] + sPart[128 + hwi] +
                   sPart[192 + hwi] + (double)pf_b[0];
        double sig = 1.0 / (1.0 + exp(-s));
        bool m = sig > (double)conf[0];
        out[MASK_OFF_ + hw] = m ? 1.0f : 0.0f;
        if (m) {
            int pos = atomicAdd(cnt, 1);
            if (pos < HW_) idxList[pos] = hw;
        }
    }
}

// ------------------------------------------------- fill cls_out with vocab_b
__global__ __launch_bounds__(256) void k_fill_cls(
    const float* __restrict__ vocab_b, float* __restrict__ out)
{
    const int total4 = NC_ * HW_ / 4;  // 7,699,200 float4s
    vfloat4* o = (vfloat4*)(out + CLS_OFF_);
    for (int i = blockIdx.x * 256 + threadIdx.x; i < total4;
         i += gridDim.x * 256) {
        int v = i / (HW_ / 4);
        float b = vocab_b[v];
        vfloat4 val = {b, b, b, b};
        __builtin_nontemporal_store(val, &o[i]);
    }
}

// ------------------------------------------------- loc 1x1 conv (64x64)
__global__ __launch_bounds__(256) void k_loc(
    const float* __restrict__ loc_feat, const float* __restrict__ loc_w,
    const float* __restrict__ loc_b, float* __restrict__ out)
{
    __shared__ float sw[16][64];
    const int tid = threadIdx.x;
    const int o0  = blockIdx.y * 16;
    for (int i = tid; i < 16 * 64; i += 256)
        sw[i >> 6][i & 63] = loc_w[(o0 + (i >> 6)) * 64 + (i & 63)];
    __syncthreads();

    const int hw = blockIdx.x * 256 + tid;
    float acc[16];
    #pragma unroll
    for (int r = 0; r < 16; ++r) acc[r] = loc_b[o0 + r];
    for (int i = 0; i < 64; ++i) {
        float f = loc_feat[(size_t)i * HW_ + hw];
        #pragma unroll
        for (int r = 0; r < 16; ++r) acc[r] += sw[r][i] * f;
    }
    #pragma unroll
    for (int r = 0; r < 16; ++r)
        out[LOC_OFF_ + (size_t)(o0 + r) * HW_ + hw] = acc[r];
}

// --------------------------- gather live columns into dense BdT[j][k] (j<capB)
__global__ __launch_bounds__(256) void k_gather(
    const float* __restrict__ cls_feat, const int* __restrict__ cnt,
    const int* __restrict__ idxList, float* __restrict__ BdT, int capB)
{
    const int count = min(*cnt, HW_);
    if (count > capB) return;  // fallback path will handle
    const int t = threadIdx.x;
    for (int j = blockIdx.x; j < count; j += gridDim.x) {
        const int hw = idxList[j];
        BdT[(size_t)j * C_ + t]       = cls_feat[(size_t)t * HW_ + hw];
        BdT[(size_t)j * C_ + 256 + t] = cls_feat[(size_t)(256 + t) * HW_ + hw];
    }
}

// --------------------------- dense GEMM over compacted columns, sync-free
// thread = (v = bx*64 + tid&63, wave-uniform column j). Full K in registers.
__global__ __launch_bounds__(256) void k_gemm_dense(
    const float* __restrict__ vocab_w, const float* __restrict__ vocab_b,
    const int* __restrict__ cnt, const int* __restrict__ idxList,
    const float* __restrict__ BdT, float* __restrict__ out, int capB)
{
    const int count = min(*cnt, HW_);
    if (count == 0 || count > capB) return;
    const int v   = blockIdx.x * 64 + (threadIdx.x & 63);
    const int jq  = threadIdx.x >> 6;  // wave index 0..3
    const bool vok = v < NC_;
    const vfloat4* a4 = (const vfloat4*)(vocab_w + (size_t)(vok ? v : 0) * C_);
    const float bias = vok ? vocab_b[v] : 0.f;

    for (int j0 = blockIdx.y * 4; j0 < count; j0 += gridDim.y * 4) {
        const int j = j0 + jq;
        if (j < count && vok) {
            const int hw = idxList[j];
            const vfloat4* b4 = (const vfloat4*)(BdT + (size_t)j * C_);
            float a0 = 0.f, a1 = 0.f, a2 = 0.f, a3 = 0.f;
            #pragma unroll 8
            for (int k = 0; k < C_ / 4; ++k) {
                vfloat4 a = a4[k], b = b4[k];
                a0 += a.x * b.x; a1 += a.y * b.y;
                a2 += a.z * b.z; a3 += a.w * b.w;
            }
            out[CLS_OFF_ + (size_t)v * HW_ + hw] = (a0 + a1) + (a2 + a3) + bias;
        }
    }
}

// --------------------------- fallback: direct scatter-gather GEMM (count>capB)
__global__ __launch_bounds__(256) void k_gemm_fallback(
    const float* __restrict__ cls_feat, const float* __restrict__ vocab_w,
    const float* __restrict__ vocab_b, const int* __restrict__ cnt,
    const int* __restrict__ idxList, float* __restrict__ out, int capB)
{
    const int count = min(*cnt, HW_);
    if (count <= capB) return;  // dense path handled it
    const int v0 = blockIdx.x * 64;

    __shared__ float sAT[16][64];
    __shared__ float sBT[16][64];
    __shared__ int   sIdx[64];

    const int tid = threadIdx.x;
    const int tx = tid & 15;
    const int ty = tid >> 4;
    const int r  = tid >> 2;
    const int kq = tid & 3;

    for (int jb = blockIdx.y; (jb << 6) < count; jb += gridDim.y) {
        const int j0 = jb << 6;
        __syncthreads();
        if (tid < 64) {
            int j = j0 + tid;
            sIdx[tid] = (j < count) ? idxList[j] : -1;
        }
        __syncthreads();
        const int hwj = sIdx[r];

        float acc[4][4] = {};
        for (int k0 = 0; k0 < C_; k0 += 16) {
            float4 a4 = make_float4(0.f, 0.f, 0.f, 0.f);
            if (v0 + r < NC_)
                a4 = *(const float4*)(vocab_w + (size_t)(v0 + r) * C_ + k0 + kq * 4);
            float b0 = 0.f, b1 = 0.f, b2 = 0.f, b3 = 0.f;
            if (hwj >= 0) {
                const float* bp = cls_feat + (size_t)(k0 + kq * 4) * HW_ + hwj;
                b0 = bp[0]; b1 = bp[HW_]; b2 = bp[2 * HW_]; b3 = bp[3 * HW_];
            }
            __syncthreads();
            sAT[kq * 4 + 0][r] = a4.x; sAT[kq * 4 + 1][r] = a4.y;
            sAT[kq * 4 + 2][r] = a4.z; sAT[kq * 4 + 3][r] = a4.w;
            sBT[kq * 4 + 0][r] = b0;   sBT[kq * 4 + 1][r] = b1;
            sBT[kq * 4 + 2][r] = b2;   sBT[kq * 4 + 3][r] = b3;
            __syncthreads();
            #pragma unroll
            for (int kk = 0; kk < 16; ++kk) {
                const float4 av = *(const float4*)&sAT[kk][ty * 4];
                const float4 bv = *(const float4*)&sBT[kk][tx * 4];
                acc[0][0] += av.x * bv.x; acc[0][1] += av.x * bv.y;
                acc[0][2] += av.x * bv.z; acc[0][3] += av.x * bv.w;
                acc[1][0] += av.y * bv.x; acc[1][1] += av.y * bv.y;
                acc[1][2] += av.y * bv.z; acc[1][3] += av.y * bv.w;
                acc[2][0] += av.z * bv.x; acc[2][1] += av.z * bv.y;
                acc[2][2] += av.z * bv.z; acc[2][3] += av.z * bv.w;
                acc[3][0] += av.w * bv.x; acc[3][1] += av.w * bv.y;
                acc[3][2] += av.w * bv.z; acc[3][3] += av.w * bv.w;
            }
        }
        #pragma unroll
        for (int a = 0; a < 4; ++a) {
            int v = v0 + ty * 4 + a;
            if (v >= NC_) continue;
            float bias = vocab_b[v];
            #pragma unroll
            for (int b = 0; b < 4; ++b) {
                int j = j0 + tx * 4 + b;
                if (j < count) {
                    int hw = sIdx[tx * 4 + b];
                    out[CLS_OFF_ + (size_t)v * HW_ + hw] = acc[a][b] + bias;
                }
            }
        }
    }
}

// ----------------------------------------------------------------- launch
extern "C" void kernel_launch(void* const* d_in, const int* in_sizes, int n_in,
                              void* d_out, int out_size, void* d_ws,
                              size_t ws_size, hipStream_t stream) {
    const float* cls_feat = (const float*)d_in[0];
    const float* loc_feat = (const float*)d_in[1];
    const float* conf     = (const float*)d_in[2];
    const float* pf_w     = (const float*)d_in[3];
    const float* pf_b     = (const float*)d_in[4];
    const float* vocab_w  = (const float*)d_in[5];
    const float* vocab_b  = (const float*)d_in[6];
    const float* loc_w    = (const float*)d_in[7];
    const float* loc_b    = (const float*)d_in[8];
    float* out = (float*)d_out;

    int*   cnt     = (int*)d_ws;
    int*   idxList = (int*)((char*)d_ws + 4096);
    size_t fixed   = 4096 + (size_t)HW_ * sizeof(int);
    float* BdT     = (float*)((char*)d_ws + fixed);

    int capB = 0;
    if (ws_size > fixed) {
        size_t cols = (ws_size - fixed) / ((size_t)C_ * sizeof(float));
        capB = (int)(cols > 2048 ? 2048 : cols);
        capB &= ~63;
    }

    hipLaunchKernelGGL(k_init, dim3(1), dim3(1), 0, stream, cnt);
    hipLaunchKernelGGL(k_pf_mask, dim3(HW_ / 64), dim3(256), 0, stream,
                       cls_feat, pf_w, pf_b, conf, out, cnt, idxList);
    hipLaunchKernelGGL(k_fill_cls, dim3(2048), dim3(256), 0, stream,
                       vocab_b, out);
    hipLaunchKernelGGL(k_loc, dim3(HW_ / 256, 4), dim3(256), 0, stream,
                       loc_feat, loc_w, loc_b, out);
    if (capB > 0) {
        hipLaunchKernelGGL(k_gather, dim3(512), dim3(256), 0, stream,
                           cls_feat, cnt, idxList, BdT, capB);
        hipLaunchKernelGGL(k_gemm_dense, dim3((NC_ + 63) / 64, 32), dim3(256),
                           0, stream, vocab_w, vocab_b, cnt, idxList, BdT, out,
                           capB);
    }
    hipLaunchKernelGGL(k_gemm_fallback, dim3((NC_ + 63) / 64, 50), dim3(256),
                       0, stream, cls_feat, vocab_w, vocab_b, cnt, idxList,
                       out, capB);
}

// Round 5
// 91.152 us; speedup vs baseline: 1.5891x; 1.5891x over previous
//
#include <hip/hip_runtime.h>
#include <math.h>

// LRPCHead: C=512, H=W=160 (HW=25600), NC=1203, LC=64
// Outputs (flat, fp32): loc_out [64*25600] | cls_out [1203*25600] | mask [25600]

constexpr int C_   = 512;
constexpr int HW_  = 25600;
constexpr int NC_  = 1203;

constexpr int LOC_OFF_  = 0;
constexpr int CLS_OFF_  = 64 * HW_;              // 1,638,400
constexpr int MASK_OFF_ = CLS_OFF_ + NC_ * HW_;  // 32,435,200

typedef float vfloat4 __attribute__((ext_vector_type(4)));

// ---------------------------------------------------------------- init
__global__ void k_init(int* cnt) { *cnt = 0; }

// ------------------------------------------------- pf score + mask + compact
__global__ __launch_bounds__(256) void k_pf_mask(
    const float* __restrict__ cls_feat, const float* __restrict__ pf_w,
    const float* __restrict__ pf_b, const float* __restrict__ conf,
    float* __restrict__ out, int* __restrict__ cnt,
    int* __restrict__ idxList)
{
    __shared__ double sPart[256];
    const int tid   = threadIdx.x;
    const int hwi   = tid & 63;
    const int slice = tid >> 6;
    const int hw    = blockIdx.x * 64 + hwi;
    const float* p  = cls_feat + (size_t)slice * 128 * HW_ + hw;
    const float* w  = pf_w + slice * 128;
    double acc = 0.0;
    #pragma unroll 4
    for (int k = 0; k < 128; ++k)
        acc += (double)w[k] * (double)p[(size_t)k * HW_];
    sPart[tid] = acc;
    __syncthreads();
    if (slice == 0) {
        double s = sPart[hwi] + sPart[64 + hwi] + sPart[128 + hwi] +
                   sPart[192 + hwi] + (double)pf_b[0];
        double sig = 1.0 / (1.0 + exp(-s));
        bool m = sig > (double)conf[0];
        out[MASK_OFF_ + hw] = m ? 1.0f : 0.0f;
        if (m) {
            int pos = atomicAdd(cnt, 1);
            if (pos < HW_) idxList[pos] = hw;
        }
    }
}

// ------------------------------------------------- fill cls_out with vocab_b
__global__ __launch_bounds__(256) void k_fill_cls(
    const float* __restrict__ vocab_b, float* __restrict__ out)
{
    const int total4 = NC_ * HW_ / 4;  // 7,699,200 float4s
    vfloat4* o = (vfloat4*)(out + CLS_OFF_);
    for (int i = blockIdx.x * 256 + threadIdx.x; i < total4;
         i += gridDim.x * 256) {
        int v = i / (HW_ / 4);
        float b = vocab_b[v];
        vfloat4 val = {b, b, b, b};
        __builtin_nontemporal_store(val, &o[i]);
    }
}

// ------------------------------------------------- loc 1x1 conv (64x64)
__global__ __launch_bounds__(256) void k_loc(
    const float* __restrict__ loc_feat, const float* __restrict__ loc_w,
    const float* __restrict__ loc_b, float* __restrict__ out)
{
    __shared__ float sw[16][64];
    const int tid = threadIdx.x;
    const int o0  = blockIdx.y * 16;
    for (int i = tid; i < 16 * 64; i += 256)
        sw[i >> 6][i & 63] = loc_w[(o0 + (i >> 6)) * 64 + (i & 63)];
    __syncthreads();

    const int hw = blockIdx.x * 256 + tid;
    float acc[16];
    #pragma unroll
    for (int r = 0; r < 16; ++r) acc[r] = loc_b[o0 + r];
    for (int i = 0; i < 64; ++i) {
        float f = loc_feat[(size_t)i * HW_ + hw];
        #pragma unroll
        for (int r = 0; r < 16; ++r) acc[r] += sw[r][i] * f;
    }
    #pragma unroll
    for (int r = 0; r < 16; ++r)
        out[LOC_OFF_ + (size_t)(o0 + r) * HW_ + hw] = acc[r];
}

// ------------- gather live columns TRANSPOSED: BdT_T[k][j], stride jcap
__global__ __launch_bounds__(256) void k_gatherT(
    const float* __restrict__ cls_feat, const int* __restrict__ cnt,
    const int* __restrict__ idxList, float* __restrict__ BdT_T, int jcap)
{
    const int count = min(*cnt, HW_);
    if (count > jcap) return;  // fallback path will handle
    const int t = threadIdx.x;
    for (int j = blockIdx.x; j < count; j += gridDim.x) {
        const int hw = idxList[j];
        BdT_T[(size_t)t * jcap + j]         = cls_feat[(size_t)t * HW_ + hw];
        BdT_T[(size_t)(256 + t) * jcap + j] = cls_feat[(size_t)(256 + t) * HW_ + hw];
    }
}

// ------------- dense GEMM: wave-uniform v (scalar A), lane->j (coalesced B)
// block = 4 waves = 4 consecutive v rows; grid (ceil(NC/4), jcap/64)
__global__ __launch_bounds__(256) void k_gemm2(
    const float* __restrict__ vocab_w, const float* __restrict__ vocab_b,
    const int* __restrict__ cnt, const int* __restrict__ idxList,
    const float* __restrict__ BdT_T, float* __restrict__ out, int jcap)
{
    const int count = min(*cnt, HW_);
    if (count == 0 || count > jcap) return;
    const int j0 = blockIdx.y * 64;
    if (j0 >= count) return;

    const int wv   = __builtin_amdgcn_readfirstlane(threadIdx.x >> 6);
    const int v    = blockIdx.x * 4 + wv;
    const int lane = threadIdx.x & 63;
    const int j    = j0 + lane;
    const bool jok = j < count;
    const int  jc  = jok ? j : 0;

    const float* __restrict__ A =
        vocab_w + (size_t)(v < NC_ ? v : NC_ - 1) * C_;
    const float* __restrict__ Bp = BdT_T + jc;

    float acc0 = 0.f, acc1 = 0.f, acc2 = 0.f, acc3 = 0.f;
    #pragma unroll 8
    for (int k = 0; k < C_; k += 4) {
        acc0 += A[k + 0] * Bp[(size_t)(k + 0) * jcap];
        acc1 += A[k + 1] * Bp[(size_t)(k + 1) * jcap];
        acc2 += A[k + 2] * Bp[(size_t)(k + 2) * jcap];
        acc3 += A[k + 3] * Bp[(size_t)(k + 3) * jcap];
    }

    if (v < NC_ && jok) {
        const int hw = idxList[j];
        out[CLS_OFF_ + (size_t)v * HW_ + hw] =
            (acc0 + acc1) + (acc2 + acc3) + vocab_b[v];
    }
}

// --------------------------- fallback: direct scatter-gather GEMM (count>jcap)
__global__ __launch_bounds__(256) void k_gemm_fallback(
    const float* __restrict__ cls_feat, const float* __restrict__ vocab_w,
    const float* __restrict__ vocab_b, const int* __restrict__ cnt,
    const int* __restrict__ idxList, float* __restrict__ out, int capB)
{
    const int count = min(*cnt, HW_);
    if (count <= capB) return;  // dense path handled it
    const int v0 = blockIdx.x * 64;

    __shared__ float sAT[16][64];
    __shared__ float sBT[16][64];
    __shared__ int   sIdx[64];

    const int tid = threadIdx.x;
    const int tx = tid & 15;
    const int ty = tid >> 4;
    const int r  = tid >> 2;
    const int kq = tid & 3;

    for (int jb = blockIdx.y; (jb << 6) < count; jb += gridDim.y) {
        const int j0 = jb << 6;
        __syncthreads();
        if (tid < 64) {
            int j = j0 + tid;
            sIdx[tid] = (j < count) ? idxList[j] : -1;
        }
        __syncthreads();
        const int hwj = sIdx[r];

        float acc[4][4] = {};
        for (int k0 = 0; k0 < C_; k0 += 16) {
            float4 a4 = make_float4(0.f, 0.f, 0.f, 0.f);
            if (v0 + r < NC_)
                a4 = *(const float4*)(vocab_w + (size_t)(v0 + r) * C_ + k0 + kq * 4);
            float b0 = 0.f, b1 = 0.f, b2 = 0.f, b3 = 0.f;
            if (hwj >= 0) {
                const float* bp = cls_feat + (size_t)(k0 + kq * 4) * HW_ + hwj;
                b0 = bp[0]; b1 = bp[HW_]; b2 = bp[2 * HW_]; b3 = bp[3 * HW_];
            }
            __syncthreads();
            sAT[kq * 4 + 0][r] = a4.x; sAT[kq * 4 + 1][r] = a4.y;
            sAT[kq * 4 + 2][r] = a4.z; sAT[kq * 4 + 3][r] = a4.w;
            sBT[kq * 4 + 0][r] = b0;   sBT[kq * 4 + 1][r] = b1;
            sBT[kq * 4 + 2][r] = b2;   sBT[kq * 4 + 3][r] = b3;
            __syncthreads();
            #pragma unroll
            for (int kk = 0; kk < 16; ++kk) {
                const float4 av = *(const float4*)&sAT[kk][ty * 4];
                const float4 bv = *(const float4*)&sBT[kk][tx * 4];
                acc[0][0] += av.x * bv.x; acc[0][1] += av.x * bv.y;
                acc[0][2] += av.x * bv.z; acc[0][3] += av.x * bv.w;
                acc[1][0] += av.y * bv.x; acc[1][1] += av.y * bv.y;
                acc[1][2] += av.y * bv.z; acc[1][3] += av.y * bv.w;
                acc[2][0] += av.z * bv.x; acc[2][1] += av.z * bv.y;
                acc[2][2] += av.z * bv.z; acc[2][3] += av.z * bv.w;
                acc[3][0] += av.w * bv.x; acc[3][1] += av.w * bv.y;
                acc[3][2] += av.w * bv.z; acc[3][3] += av.w * bv.w;
            }
        }
        #pragma unroll
        for (int a = 0; a < 4; ++a) {
            int v = v0 + ty * 4 + a;
            if (v >= NC_) continue;
            float bias = vocab_b[v];
            #pragma unroll
            for (int b = 0; b < 4; ++b) {
                int j = j0 + tx * 4 + b;
                if (j < count) {
                    int hw = sIdx[tx * 4 + b];
                    out[CLS_OFF_ + (size_t)v * HW_ + hw] = acc[a][b] + bias;
                }
            }
        }
    }
}

// ----------------------------------------------------------------- launch
extern "C" void kernel_launch(void* const* d_in, const int* in_sizes, int n_in,
                              void* d_out, int out_size, void* d_ws,
                              size_t ws_size, hipStream_t stream) {
    const float* cls_feat = (const float*)d_in[0];
    const float* loc_feat = (const float*)d_in[1];
    const float* conf     = (const float*)d_in[2];
    const float* pf_w     = (const float*)d_in[3];
    const float* pf_b     = (const float*)d_in[4];
    const float* vocab_w  = (const float*)d_in[5];
    const float* vocab_b  = (const float*)d_in[6];
    const float* loc_w    = (const float*)d_in[7];
    const float* loc_b    = (const float*)d_in[8];
    float* out = (float*)d_out;

    int*   cnt     = (int*)d_ws;
    int*   idxList = (int*)((char*)d_ws + 4096);
    size_t fixed   = 4096 + (size_t)HW_ * sizeof(int);
    float* BdT_T   = (float*)((char*)d_ws + fixed);

    int jcap = 0;
    if (ws_size > fixed) {
        size_t cols = (ws_size - fixed) / ((size_t)C_ * sizeof(float));
        jcap = (int)(cols > 1024 ? 1024 : cols);
        jcap &= ~63;
    }

    hipLaunchKernelGGL(k_init, dim3(1), dim3(1), 0, stream, cnt);
    hipLaunchKernelGGL(k_pf_mask, dim3(HW_ / 64), dim3(256), 0, stream,
                       cls_feat, pf_w, pf_b, conf, out, cnt, idxList);
    hipLaunchKernelGGL(k_fill_cls, dim3(2048), dim3(256), 0, stream,
                       vocab_b, out);
    hipLaunchKernelGGL(k_loc, dim3(HW_ / 256, 4), dim3(256), 0, stream,
                       loc_feat, loc_w, loc_b, out);
    if (jcap > 0) {
        hipLaunchKernelGGL(k_gatherT, dim3(512), dim3(256), 0, stream,
                           cls_feat, cnt, idxList, BdT_T, jcap);
        hipLaunchKernelGGL(k_gemm2, dim3((NC_ + 3) / 4, jcap / 64), dim3(256),
                           0, stream, vocab_w, vocab_b, cnt, idxList, BdT_T,
                           out, jcap);
    }
    hipLaunchKernelGGL(k_gemm_fallback, dim3((NC_ + 63) / 64, 50), dim3(256),
                       0, stream, cls_feat, vocab_w, vocab_b, cnt, idxList,
                       out, jcap);
}